// Round 9
// baseline (29.460 us; speedup 1.0000x reference)
//
#include <hip/hip_runtime.h>
#include <hip/hip_bf16.h>

// Single fused kernel: block = sample (2048 blocks x 256 thr = 4 waves).
// Wave g owns rows [g*64, g*64+64) and [g*64+256, g*64+320) (<=2 tiles).
// Changes vs R8:
//  - A-frags and B-frags are DIRECT strided loads (lanes 0-15), not
//    stage+ds_bpermute: removes ~36 DS-pipe ops/wave (shared-pipe congestion).
//  - Tile loads are wave-uniform-conditional on len again (len s_load issues
//    first; tile-0 cat loads overlap it). Cuts ~48MB -> ~30MB of L2/L3 traffic.
//  - 101-row embedding matvec uses 4 accumulators (breaks dependent FMA chain).
// Main compute per tile:
//   - 95-bin LDS-atomic histogram (4 big tables) + packed binary ones-counts
//   - cont colsum(relu(X@W_cont + b)) via mfma_f32_16x16x32_bf16
//     (K=6 real: x0..x4 + bias-aug 1; lanes 0-15 = k-group 0; zero-padded)
// Epilogue (3 barriers): bin weights -> embedding matvec (waves 0,1, lane=dim)
//   -> W1 stripes (shfl bcast / LDS cont-mean) -> relu -> W2 butterfly.

#define CARD3 11
#define CARD4 19
#define CARD5 31
#define CARD6 34

typedef __attribute__((ext_vector_type(8))) short bf16x8;
typedef __attribute__((ext_vector_type(4))) float f32x4;
typedef __attribute__((ext_vector_type(4))) unsigned uintx4;
typedef int   int4a  __attribute__((ext_vector_type(4), aligned(4)));
typedef int   int2a  __attribute__((ext_vector_type(2), aligned(4)));
typedef float flt4a  __attribute__((ext_vector_type(4), aligned(4)));

static __device__ __forceinline__ unsigned pk_bf16(float a, float b) {
    unsigned ua = __float_as_uint(a), ub = __float_as_uint(b);
    ua += 0x7FFFu + ((ua >> 16) & 1u);      // round-to-nearest-even
    ub += 0x7FFFu + ((ub >> 16) & 1u);
    return ((ua >> 16) & 0xFFFFu) | (ub & 0xFFFF0000u);
}

__global__ __launch_bounds__(256) void mlp_fused(
    const float* __restrict__ cont_x,   // [B,S,5]
    const int*   __restrict__ cat_x,    // [B,S,7]
    const int*   __restrict__ length,   // [B]
    const float* __restrict__ e0, const float* __restrict__ e1,
    const float* __restrict__ e2, const float* __restrict__ e3,
    const float* __restrict__ e4, const float* __restrict__ e5,
    const float* __restrict__ e6,
    const float* __restrict__ W_cont,   // [5,64]
    const float* __restrict__ b_cont,   // [64]
    const float* __restrict__ W1,       // [128,64]
    const float* __restrict__ b1,       // [64]
    const float* __restrict__ W2,       // [64,2]
    const float* __restrict__ b2,       // [2]
    float*       __restrict__ out,      // [B,2]
    int S)
{
    constexpr int HOFF[4] = {0, 11, 30, 61};
    constexpr int CARD[7] = {2, 2, 2, CARD3, CARD4, CARD5, CARD6};
    constexpr int OFFB[7] = {0, 2, 4, 6, 17, 36, 67};

    __shared__ int   hist[4][96];
    __shared__ int   bc_s[4];
    __shared__ float pcont[4][64];
    __shared__ float w[104];
    __shared__ float cmean[64];
    __shared__ float partW1[4][64];

    const int b    = blockIdx.x;
    const int tid  = threadIdx.x;
    const int g    = tid >> 6;
    const int l    = tid & 63;
    const int lo16 = l & 15;
    const bool lo  = (l < 16);

    const int len = length[b];          // block-uniform s_load, issued first

    const size_t sbase = (size_t)b * S;

    // tile-0 per-lane cat loads: row g*64+l <= 255 < S, always safe
    const int* cp0 = cat_x + (sbase + g * 64 + l) * 7;
    const int4a ca0 = *(const int4a*)cp0;
    const int2a cb0 = *(const int2a*)(cp0 + 4);
    const int   cc0 = cp0[6];

    const bool has_t0 = (len > g * 64);          // wave-uniform
    const bool has_t1 = (len > g * 64 + 256);    // wave-uniform

    int4a ca1 = {0, 0, 0, 0}; int2a cb1 = {0, 0}; int cc1 = 0;
    if (has_t1) {
        const int* cp1 = cat_x + (sbase + g * 64 + 256 + l) * 7;
        ca1 = *(const int4a*)cp1;
        cb1 = *(const int2a*)(cp1 + 4);
        cc1 = cp1[6];
    }

    // zero own wave's private histogram (same-wave DS ordering, no barrier)
    hist[g][l] = 0;
    if (l < 32) hist[g][64 + l] = 0;

    // ---- B-frags: direct loads, lanes 0-15 hold col nt*16+lo16 ----
    bf16x8 Bf[4];
#pragma unroll
    for (int nt = 0; nt < 4; ++nt) {
        float w0 = 0.f, w1 = 0.f, w2 = 0.f, w3 = 0.f, w4 = 0.f, w5 = 0.f;
        if (lo) {
            const int c = nt * 16 + lo16;
            w0 = W_cont[c];       w1 = W_cont[64 + c];
            w2 = W_cont[128 + c]; w3 = W_cont[192 + c];
            w4 = W_cont[256 + c]; w5 = b_cont[c];
        }
        const uintx4 bu = {pk_bf16(w0, w1), pk_bf16(w2, w3), pk_bf16(w4, w5), 0u};
        Bf[nt] = __builtin_bit_cast(bf16x8, bu);
    }

    int   c1pack = 0;
    f32x4 sum0 = {0.f, 0.f, 0.f, 0.f};
    f32x4 sum1 = sum0, sum2 = sum0, sum3 = sum0;
    const f32x4 z = {0.f, 0.f, 0.f, 0.f};

    auto do_tile = [&](int base, int4a ca, int2a cb, int cc) {
        const bool valid = (base + l < len);
        if (valid) {
            c1pack += ca.x + (ca.y << 8) + (ca.z << 16);
            atomicAdd(&hist[g][HOFF[0] + ca.w], 1);
            atomicAdd(&hist[g][HOFF[1] + cb.x], 1);
            atomicAdd(&hist[g][HOFF[2] + cb.y], 1);
            atomicAdd(&hist[g][HOFF[3] + cc],   1);
        }
#pragma unroll
        for (int t = 0; t < 4; ++t) {
            const int r = base + t * 16 + lo16;      // r <= 511 < S always
            float y0 = 0.f, y1 = 0.f, y2 = 0.f, y3 = 0.f, y4 = 0.f, aug = 0.f;
            if (lo) {
                const float* xp = cont_x + (sbase + r) * 5;
                const flt4a xa = *(const flt4a*)xp;
                const float xb = xp[4];
                if (r < len) {
                    y0 = xa.x; y1 = xa.y; y2 = xa.z; y3 = xa.w; y4 = xb;
                    aug = 1.f;
                }
            }
            const uintx4 au = {pk_bf16(y0, y1), pk_bf16(y2, y3), pk_bf16(y4, aug), 0u};
            const bf16x8 Af = __builtin_bit_cast(bf16x8, au);

            const f32x4 d0 = __builtin_amdgcn_mfma_f32_16x16x32_bf16(Af, Bf[0], z, 0, 0, 0);
            const f32x4 d1 = __builtin_amdgcn_mfma_f32_16x16x32_bf16(Af, Bf[1], z, 0, 0, 0);
            const f32x4 d2 = __builtin_amdgcn_mfma_f32_16x16x32_bf16(Af, Bf[2], z, 0, 0, 0);
            const f32x4 d3 = __builtin_amdgcn_mfma_f32_16x16x32_bf16(Af, Bf[3], z, 0, 0, 0);
#pragma unroll
            for (int i = 0; i < 4; ++i) {
                sum0[i] += fmaxf(d0[i], 0.f);
                sum1[i] += fmaxf(d1[i], 0.f);
                sum2[i] += fmaxf(d2[i], 0.f);
                sum3[i] += fmaxf(d3[i], 0.f);
            }
        }
    };

    if (has_t0) do_tile(g * 64,       ca0, cb0, cc0);
    if (has_t1) do_tile(g * 64 + 256, ca1, cb1, cc1);

    // packed binary count reduce (fields <= 128 per wave)
#pragma unroll
    for (int off = 1; off <= 32; off <<= 1) c1pack += __shfl_xor(c1pack, off);
    if (l == 0) bc_s[g] = c1pack;

    // cont col sums -> pcont[g][0..63]
    float s0 = sum0[0] + sum0[1] + sum0[2] + sum0[3];
    float s1 = sum1[0] + sum1[1] + sum1[2] + sum1[3];
    float s2 = sum2[0] + sum2[1] + sum2[2] + sum2[3];
    float s3 = sum3[0] + sum3[1] + sum3[2] + sum3[3];
    s0 += __shfl_xor(s0, 16); s0 += __shfl_xor(s0, 32);
    s1 += __shfl_xor(s1, 16); s1 += __shfl_xor(s1, 32);
    s2 += __shfl_xor(s2, 16); s2 += __shfl_xor(s2, 32);
    s3 += __shfl_xor(s3, 16); s3 += __shfl_xor(s3, 32);
    if (lo) {
        pcont[g][lo16]      = s0;
        pcont[g][16 + lo16] = s1;
        pcont[g][32 + lo16] = s2;
        pcont[g][48 + lo16] = s3;
    }
    __syncthreads();                                   // B1

    const float inv_len = 1.0f / (float)len;
    const float inv7    = inv_len * (1.0f / 7.0f);

    if (tid < 95) {
        const int h = hist[0][tid] + hist[1][tid] + hist[2][tid] + hist[3][tid];
        w[6 + tid] = (float)h * inv7;
    } else if (tid >= 96 && tid < 99) {
        const int j = tid - 96;
        const int c1 = ((bc_s[0] >> (8 * j)) & 0xFF) + ((bc_s[1] >> (8 * j)) & 0xFF)
                     + ((bc_s[2] >> (8 * j)) & 0xFF) + ((bc_s[3] >> (8 * j)) & 0xFF);
        w[2 * j + 1] = (float)c1 * inv7;
        w[2 * j]     = (float)(len - c1) * inv7;
    }
    if (tid >= 128 && tid < 192) {
        const int d = tid - 128;
        cmean[d] = (pcont[0][d] + pcont[1][d] + pcont[2][d] + pcont[3][d]) * inv_len;
    }
    __syncthreads();                                   // B2

    // waves 0,1: 101-row weighted embedding matvec, 4 accumulators
    float pcv = 0.f;
    if (g < 2) {
        float a0 = 0.f, a1v = 0.f, a2v = 0.f, a3v = 0.f;
#pragma unroll
        for (int t = 0; t < 7; ++t) {
            const float* tab = (t == 0) ? e0 : (t == 1) ? e1 : (t == 2) ? e2
                             : (t == 3) ? e3 : (t == 4) ? e4 : (t == 5) ? e5 : e6;
#pragma unroll
            for (int v = 0; v < CARD[t]; ++v) {
                const int i = OFFB[t] + v;             // compile-time
                const float f = w[i] ;
                const float ev = tab[v * 64 + l];
                if ((i & 3) == 0)      a0  = fmaf(f, ev, a0);
                else if ((i & 3) == 1) a1v = fmaf(f, ev, a1v);
                else if ((i & 3) == 2) a2v = fmaf(f, ev, a2v);
                else                   a3v = fmaf(f, ev, a3v);
            }
        }
        pcv = (a0 + a1v) + (a2v + a3v);
    }

    // W1: wave g handles input dims [32g, 32g+32)
    {
        float a1 = (g == 0) ? b1[l] : 0.f;
        if (g < 2) {
            const int d0 = g * 32;
#pragma unroll
            for (int i = 0; i < 32; ++i) {
                const int d = d0 + i;
                a1 = fmaf(__shfl(pcv, d), W1[d * 64 + l], a1);   // intra-wave bcast
            }
        } else {
            const int d0 = (g - 2) * 32;
#pragma unroll 8
            for (int i = 0; i < 32; ++i) {
                const int d = d0 + i;
                a1 = fmaf(cmean[d], W1[(64 + d) * 64 + l], a1);
            }
        }
        partW1[g][l] = a1;
    }
    __syncthreads();                                   // B3

    if (tid < 64) {
        const float h = fmaxf(partW1[0][l] + partW1[1][l]
                            + partW1[2][l] + partW1[3][l], 0.f);
        const float2 w2v = ((const float2*)W2)[l];
        float rr0 = h * w2v.x;
        float rr1 = h * w2v.y;
#pragma unroll
        for (int off = 1; off <= 32; off <<= 1) {
            rr0 += __shfl_xor(rr0, off);
            rr1 += __shfl_xor(rr1, off);
        }
        if (l == 0) {
            const float2 bb2 = *(const float2*)b2;
            float2 res;
            res.x = fmaxf(rr0 + bb2.x, 0.f);
            res.y = fmaxf(rr1 + bb2.y, 0.f);
            ((float2*)out)[b] = res;
        }
    }
}

extern "C" void kernel_launch(void* const* d_in, const int* in_sizes, int n_in,
                              void* d_out, int out_size, void* d_ws, size_t ws_size,
                              hipStream_t stream)
{
    const float* cont_x = (const float*)d_in[0];
    const int*   cat_x  = (const int*)d_in[1];
    const int*   length = (const int*)d_in[2];
    const float* e0     = (const float*)d_in[3];
    const float* e1     = (const float*)d_in[4];
    const float* e2     = (const float*)d_in[5];
    const float* e3     = (const float*)d_in[6];
    const float* e4     = (const float*)d_in[7];
    const float* e5     = (const float*)d_in[8];
    const float* e6     = (const float*)d_in[9];
    const float* W_cont = (const float*)d_in[10];
    const float* b_cont = (const float*)d_in[11];
    const float* W1     = (const float*)d_in[12];
    const float* b1     = (const float*)d_in[13];
    const float* W2     = (const float*)d_in[14];
    const float* b2     = (const float*)d_in[15];
    float*       out    = (float*)d_out;

    const int B = in_sizes[2];                 // 2048
    const int S = in_sizes[0] / (B * 5);       // 512

    hipLaunchKernelGGL(mlp_fused, dim3(B), dim3(256), 0, stream,
                       cont_x, cat_x, length,
                       e0, e1, e2, e3, e4, e5, e6,
                       W_cont, b_cont, W1, b1, W2, b2,
                       out, S);
}

// Round 10
// 19.825 us; speedup vs baseline: 1.4860x; 1.4860x over previous
//
#include <hip/hip_runtime.h>
#include <hip/hip_bf16.h>

// One WAVE per sample (2048 blocks x 64 threads). Zero barriers.
// Per wave: up to 8 tiles of 64 rows, ping-pong depth-2 prefetch (all row
// addresses < S are len-safe; loads gated only by wave-uniform tile count).
// Per tile: 95-bin LDS-atomic histogram (block-private) + 10-bit packed binary
// ones-counts + cont colsum(relu(X@W_cont+b)) via mfma_f32_16x16x32_bf16.
// Epilogue fully intra-wave: bin weights in 2 lane-sliced regs, 101-row
// embedding matvec + W1(128x64) via v_readlane broadcasts (SALU), W2 butterfly.

#define CARD3 11
#define CARD4 19
#define CARD5 31
#define CARD6 34

typedef __attribute__((ext_vector_type(8))) short bf16x8;
typedef __attribute__((ext_vector_type(4))) float f32x4;
typedef __attribute__((ext_vector_type(4))) unsigned uintx4;
typedef int   int4a  __attribute__((ext_vector_type(4), aligned(4)));
typedef int   int2a  __attribute__((ext_vector_type(2), aligned(4)));
typedef float flt4a  __attribute__((ext_vector_type(4), aligned(4)));

static __device__ __forceinline__ unsigned pk_bf16(float a, float b) {
    unsigned ua = __float_as_uint(a), ub = __float_as_uint(b);
    ua += 0x7FFFu + ((ua >> 16) & 1u);      // round-to-nearest-even
    ub += 0x7FFFu + ((ub >> 16) & 1u);
    return ((ua >> 16) & 0xFFFFu) | (ub & 0xFFFF0000u);
}

static __device__ __forceinline__ float rdlane(float v, int i) {
    return __builtin_bit_cast(float,
        __builtin_amdgcn_readlane(__builtin_bit_cast(int, v), i));
}

__global__ __launch_bounds__(64) void mlp_wave(
    const float* __restrict__ cont_x,   // [B,S,5]
    const int*   __restrict__ cat_x,    // [B,S,7]
    const int*   __restrict__ length,   // [B]
    const float* __restrict__ e0, const float* __restrict__ e1,
    const float* __restrict__ e2, const float* __restrict__ e3,
    const float* __restrict__ e4, const float* __restrict__ e5,
    const float* __restrict__ e6,
    const float* __restrict__ W_cont,   // [5,64]
    const float* __restrict__ b_cont,   // [64]
    const float* __restrict__ W1,       // [128,64]
    const float* __restrict__ b1,       // [64]
    const float* __restrict__ W2,       // [64,2]
    const float* __restrict__ b2,       // [2]
    float*       __restrict__ out,      // [B,2]
    int S)
{
    constexpr int HOFF[4] = {0, 11, 30, 61};
    constexpr int CARD[7] = {2, 2, 2, CARD3, CARD4, CARD5, CARD6};
    constexpr int OFFB[7] = {0, 2, 4, 6, 17, 36, 67};

    __shared__ int   hist[96];
    __shared__ float pcontl[64];

    const int b    = blockIdx.x;
    const int l    = threadIdx.x;       // 0..63
    const int lo16 = l & 15;
    const bool lo  = (l < 16);

    const int len = length[b];          // uniform s_load
    const int nt  = (len + 63) >> 6;    // 1..8 tiles

    // zero block-private histogram (same-wave DS ordering)
    hist[l] = 0;
    if (l < 32) hist[64 + l] = 0;

    const int*   cat7  = cat_x  + (size_t)b * S * 7;
    const float* cont5 = cont_x + (size_t)b * S * 5;

    // ---- B-frags: staged coalesced + shfl (R8 pattern) ----
    unsigned q0, q1, q2;
    {
        const float w0 = W_cont[l],        w1 = W_cont[64 + l];
        const float w2 = W_cont[128 + l],  w3 = W_cont[192 + l];
        const float w4 = W_cont[256 + l],  w5 = b_cont[l];
        q0 = pk_bf16(w0, w1); q1 = pk_bf16(w2, w3); q2 = pk_bf16(w4, w5);
    }
    bf16x8 Bf[4];
#pragma unroll
    for (int ntc = 0; ntc < 4; ++ntc) {
        const int src = ntc * 16 + lo16;
        unsigned c0 = (unsigned)__shfl((int)q0, src);
        unsigned c1 = (unsigned)__shfl((int)q1, src);
        unsigned c2 = (unsigned)__shfl((int)q2, src);
        c0 = lo ? c0 : 0u; c1 = lo ? c1 : 0u; c2 = lo ? c2 : 0u;
        const uintx4 bu = {c0, c1, c2, 0u};
        Bf[ntc] = __builtin_bit_cast(bf16x8, bu);
    }

    int   c1pack = 0;                       // 3x 10-bit packed ones-counts
    f32x4 sum0 = {0.f, 0.f, 0.f, 0.f};
    f32x4 sum1 = sum0, sum2 = sum0, sum3 = sum0;
    const f32x4 z = {0.f, 0.f, 0.f, 0.f};

    // ping-pong staging registers (explicit names, rule #20)
    int4a caA = {0,0,0,0}, caB = {0,0,0,0};
    int2a cbA = {0,0},     cbB = {0,0};
    int   ccA = 0,         ccB = 0;
    flt4a xaA = {0,0,0,0}, xaB = {0,0,0,0};
    float xbA = 0.f,       xbB = 0.f;

#define LOADA(T) do { const int* cp_ = cat7 + (size_t)((T)*64 + l) * 7;          \
        caA = *(const int4a*)cp_; cbA = *(const int2a*)(cp_ + 4); ccA = cp_[6];  \
        const float* xp_ = cont5 + (size_t)((T)*64 + l) * 5;                     \
        xaA = *(const flt4a*)xp_; xbA = xp_[4]; } while (0)
#define LOADB(T) do { const int* cp_ = cat7 + (size_t)((T)*64 + l) * 7;          \
        caB = *(const int4a*)cp_; cbB = *(const int2a*)(cp_ + 4); ccB = cp_[6];  \
        const float* xp_ = cont5 + (size_t)((T)*64 + l) * 5;                     \
        xaB = *(const flt4a*)xp_; xbB = xp_[4]; } while (0)

    auto COMPUTE = [&](int base, const int4a& ca, const int2a& cb, int cc,
                       const flt4a& xa, float xb) {
        const bool valid = (base + l < len);
        float x0 = 0.f, x1 = 0.f, x2 = 0.f, x3 = 0.f, x4 = 0.f;
        if (valid) {
            c1pack += ca.x + (ca.y << 10) + (ca.z << 20);
            atomicAdd(&hist[HOFF[0] + ca.w], 1);
            atomicAdd(&hist[HOFF[1] + cb.x], 1);
            atomicAdd(&hist[HOFF[2] + cb.y], 1);
            atomicAdd(&hist[HOFF[3] + cc],   1);
            x0 = xa.x; x1 = xa.y; x2 = xa.z; x3 = xa.w; x4 = xb;
        }
        const float aug = valid ? 1.0f : 0.0f;
        const unsigned p0 = pk_bf16(x0, x1);
        const unsigned p1 = pk_bf16(x2, x3);
        const unsigned p2 = pk_bf16(x4, aug);

#pragma unroll
        for (int t4 = 0; t4 < 4; ++t4) {
            const int src = t4 * 16 + lo16;
            unsigned a0 = (unsigned)__shfl((int)p0, src);
            unsigned a1 = (unsigned)__shfl((int)p1, src);
            unsigned a2 = (unsigned)__shfl((int)p2, src);
            a0 = lo ? a0 : 0u; a1 = lo ? a1 : 0u; a2 = lo ? a2 : 0u;
            const uintx4 au = {a0, a1, a2, 0u};
            const bf16x8 Af = __builtin_bit_cast(bf16x8, au);

            const f32x4 d0 = __builtin_amdgcn_mfma_f32_16x16x32_bf16(Af, Bf[0], z, 0, 0, 0);
            const f32x4 d1 = __builtin_amdgcn_mfma_f32_16x16x32_bf16(Af, Bf[1], z, 0, 0, 0);
            const f32x4 d2 = __builtin_amdgcn_mfma_f32_16x16x32_bf16(Af, Bf[2], z, 0, 0, 0);
            const f32x4 d3 = __builtin_amdgcn_mfma_f32_16x16x32_bf16(Af, Bf[3], z, 0, 0, 0);
#pragma unroll
            for (int i = 0; i < 4; ++i) {
                sum0[i] += fmaxf(d0[i], 0.f);
                sum1[i] += fmaxf(d1[i], 0.f);
                sum2[i] += fmaxf(d2[i], 0.f);
                sum3[i] += fmaxf(d3[i], 0.f);
            }
        }
    };

    // ---- software-pipelined tile loop (wave-uniform branches) ----
    LOADA(0);
    if (nt > 1) LOADB(1);
#pragma unroll 1
    for (int t = 0; t < nt; t += 2) {
        COMPUTE(t * 64, caA, cbA, ccA, xaA, xbA);
        if (t + 2 < nt) LOADA(t + 2);
        if (t + 1 < nt) {
            COMPUTE((t + 1) * 64, caB, cbB, ccB, xaB, xbB);
            if (t + 3 < nt) LOADB(t + 3);
        }
    }
#undef LOADA
#undef LOADB

    // ---- intra-wave reductions ----
#pragma unroll
    for (int off = 1; off <= 32; off <<= 1) c1pack += __shfl_xor(c1pack, off);

    float s0 = sum0[0] + sum0[1] + sum0[2] + sum0[3];
    float s1 = sum1[0] + sum1[1] + sum1[2] + sum1[3];
    float s2 = sum2[0] + sum2[1] + sum2[2] + sum2[3];
    float s3 = sum3[0] + sum3[1] + sum3[2] + sum3[3];
    s0 += __shfl_xor(s0, 16); s0 += __shfl_xor(s0, 32);
    s1 += __shfl_xor(s1, 16); s1 += __shfl_xor(s1, 32);
    s2 += __shfl_xor(s2, 16); s2 += __shfl_xor(s2, 32);
    s3 += __shfl_xor(s3, 16); s3 += __shfl_xor(s3, 32);
    if (lo) {
        pcontl[lo16]      = s0;
        pcontl[16 + lo16] = s1;
        pcontl[32 + lo16] = s2;
        pcontl[48 + lo16] = s3;
    }

    const float inv_len = 1.0f / (float)len;
    const float inv7    = inv_len * (1.0f / 7.0f);

    // lane = dim: cont mean (same-wave LDS write->read, hw-ordered via waitcnt)
    const float cmean = pcontl[l] * inv_len;

    // bin weights, lane-sliced: wA = bins 0..63, wB = bins 64..100
    float wA, wB;
    {
        const int j  = l >> 1;
        const int c1 = (c1pack >> (10 * j)) & 0x3FF;
        const float bw = (l & 1) ? (float)c1 : (float)(len - c1);
        wA = (l < 6) ? bw * inv7 : (float)hist[l - 6] * inv7;
        wB = (l < 37) ? (float)hist[58 + l] * inv7 : 0.f;
    }

    // ---- 101-row weighted embedding matvec, lane = dim, readlane bcast ----
    float pa0 = 0.f, pa1 = 0.f, pa2 = 0.f, pa3 = 0.f;
    {
        int cnt = 0;
#pragma unroll
        for (int t = 0; t < 7; ++t) {
            const float* tab = (t == 0) ? e0 : (t == 1) ? e1 : (t == 2) ? e2
                             : (t == 3) ? e3 : (t == 4) ? e4 : (t == 5) ? e5 : e6;
#pragma unroll
            for (int v = 0; v < CARD[t]; ++v) {
                const int i = OFFB[t] + v;               // compile-time
                const float f = (i < 64) ? rdlane(wA, i) : rdlane(wB, i - 64);
                const float ev = tab[v * 64 + l];
                if ((cnt & 3) == 0)      pa0 = fmaf(f, ev, pa0);
                else if ((cnt & 3) == 1) pa1 = fmaf(f, ev, pa1);
                else if ((cnt & 3) == 2) pa2 = fmaf(f, ev, pa2);
                else                     pa3 = fmaf(f, ev, pa3);
                ++cnt;
            }
        }
    }
    const float pcv = (pa0 + pa1) + (pa2 + pa3);         // pooled cat dim l

    // ---- W1: h[l] = relu(b1 + sum_d pooled[d] * W1[d][l]) ----
    float h0 = b1[l], h1 = 0.f, h2 = 0.f, h3 = 0.f;
#pragma unroll
    for (int d = 0; d < 64; ++d) {
        const float f = rdlane(pcv, d);
        const float wv = W1[d * 64 + l];
        if ((d & 3) == 0)      h0 = fmaf(f, wv, h0);
        else if ((d & 3) == 1) h1 = fmaf(f, wv, h1);
        else if ((d & 3) == 2) h2 = fmaf(f, wv, h2);
        else                   h3 = fmaf(f, wv, h3);
    }
#pragma unroll
    for (int d = 0; d < 64; ++d) {
        const float f = rdlane(cmean, d);
        const float wv = W1[(64 + d) * 64 + l];
        if ((d & 3) == 0)      h0 = fmaf(f, wv, h0);
        else if ((d & 3) == 1) h1 = fmaf(f, wv, h1);
        else if ((d & 3) == 2) h2 = fmaf(f, wv, h2);
        else                   h3 = fmaf(f, wv, h3);
    }
    const float h = fmaxf((h0 + h1) + (h2 + h3), 0.f);

    // ---- W2 butterfly + store ----
    const float2 w2v = ((const float2*)W2)[l];
    float rr0 = h * w2v.x;
    float rr1 = h * w2v.y;
#pragma unroll
    for (int off = 1; off <= 32; off <<= 1) {
        rr0 += __shfl_xor(rr0, off);
        rr1 += __shfl_xor(rr1, off);
    }
    if (l == 0) {
        const float2 bb2 = *(const float2*)b2;
        float2 res;
        res.x = fmaxf(rr0 + bb2.x, 0.f);
        res.y = fmaxf(rr1 + bb2.y, 0.f);
        ((float2*)out)[b] = res;
    }
}

extern "C" void kernel_launch(void* const* d_in, const int* in_sizes, int n_in,
                              void* d_out, int out_size, void* d_ws, size_t ws_size,
                              hipStream_t stream)
{
    const float* cont_x = (const float*)d_in[0];
    const int*   cat_x  = (const int*)d_in[1];
    const int*   length = (const int*)d_in[2];
    const float* e0     = (const float*)d_in[3];
    const float* e1     = (const float*)d_in[4];
    const float* e2     = (const float*)d_in[5];
    const float* e3     = (const float*)d_in[6];
    const float* e4     = (const float*)d_in[7];
    const float* e5     = (const float*)d_in[8];
    const float* e6     = (const float*)d_in[9];
    const float* W_cont = (const float*)d_in[10];
    const float* b_cont = (const float*)d_in[11];
    const float* W1     = (const float*)d_in[12];
    const float* b1     = (const float*)d_in[13];
    const float* W2     = (const float*)d_in[14];
    const float* b2     = (const float*)d_in[15];
    float*       out    = (float*)d_out;

    const int B = in_sizes[2];                 // 2048
    const int S = in_sizes[0] / (B * 5);       // 512

    hipLaunchKernelGGL(mlp_wave, dim3(B), dim3(64), 0, stream,
                       cont_x, cat_x, length,
                       e0, e1, e2, e3, e4, e5, e6,
                       W_cont, b_cont, W1, b1, W2, b2,
                       out, S);
}